// Round 24
// baseline (132.172 us; speedup 1.0000x reference)
//
#include <hip/hip_runtime.h>

#define NB 2048
#define NS 1024
#define NL 32

typedef short bf16x8 __attribute__((ext_vector_type(8)));
typedef float f32x16 __attribute__((ext_vector_type(16)));
union FragU { unsigned u[4]; bf16x8 v; };

static __device__ __forceinline__ float fexp2(float x) {
#if __has_builtin(__builtin_amdgcn_exp2f)
  return __builtin_amdgcn_exp2f(x);
#else
  float r; asm("v_exp_f32 %0, %1" : "=v"(r) : "v"(x)); return r;
#endif
}
static __device__ __forceinline__ float flog2(float x) {
#if __has_builtin(__builtin_amdgcn_logf)
  return __builtin_amdgcn_logf(x);
#else
  float r; asm("v_log_f32 %0, %1" : "=v"(r) : "v"(x)); return r;
#endif
}

template<int K>
static __device__ __forceinline__ int roti(int x) {
  if constexpr (K == 0) return x;
  else return __builtin_amdgcn_update_dpp(0, x, 0x120 | K, 0xf, 0xf, true); // row_ror:K
}

// permlane swaps with s_nop hazard guards (R10-validated pattern)
static __device__ __forceinline__ void plswap32_pair(unsigned &x, unsigned &y) {
  asm volatile("s_nop 1\n\tv_permlane32_swap_b32 %0, %1\n\ts_nop 1"
               : "+v"(x), "+v"(y));
}
static __device__ __forceinline__ float plswap16_sum(float part) {
  float x, y;
  asm volatile("v_mov_b32 %0, %2\n\tv_mov_b32 %1, %2\n\ts_nop 1\n\t"
               "v_permlane16_swap_b32 %0, %1\n\ts_nop 1"
               : "=&v"(x), "=&v"(y) : "v"(part));
  return x + y;
}
static __device__ __forceinline__ float plswap32_sum(float part) {
  float x, y;
  asm volatile("v_mov_b32 %0, %2\n\tv_mov_b32 %1, %2\n\ts_nop 1\n\t"
               "v_permlane32_swap_b32 %0, %1\n\ts_nop 1"
               : "=&v"(x), "=&v"(y) : "v"(part));
  return x + y;
}
static __device__ __forceinline__ float plswap32_max(float part) {
  float x, y;
  asm volatile("v_mov_b32 %0, %2\n\tv_mov_b32 %1, %2\n\ts_nop 1\n\t"
               "v_permlane32_swap_b32 %0, %1\n\ts_nop 1"
               : "=&v"(x), "=&v"(y) : "v"(part));
  return fmaxf(x, y);
}
static __device__ __forceinline__ int plswap16_partner(int lane) {
  int x, y;
  asm volatile("v_mov_b32 %0, %2\n\tv_mov_b32 %1, %2\n\ts_nop 1\n\t"
               "v_permlane16_swap_b32 %0, %1\n\ts_nop 1"
               : "=&v"(x), "=&v"(y) : "v"(lane));
  return x + y - lane;
}

// pack two f32 -> bf16x2 (src0 -> lo)
static __device__ __forceinline__ unsigned cvtpk(float a, float b) {
  unsigned r;
  asm("v_cvt_pk_bf16_f32 %0, %1, %2" : "=v"(r) : "v"(a), "v"(b));
  return r;
}
static __device__ __forceinline__ float bf2f(unsigned short u) {
  return __int_as_float(((int)u) << 16);
}

// 16-term rotate/FMA tree, DPP-fused (R23-validated; same row_ror perm as roti<K>)
static __device__ __forceinline__ float tree16f(float p, const float* E) {
  float a0 = 0.0f, a1 = 0.0f, a2 = 0.0f, a3 = 0.0f;
  asm volatile(
    "s_nop 1\n\t"
    "v_mul_f32 %0, %4, %5\n\t"
    "v_mul_f32_dpp %1, %4, %6 row_ror:1 row_mask:0xf bank_mask:0xf\n\t"
    "v_mul_f32_dpp %2, %4, %7 row_ror:2 row_mask:0xf bank_mask:0xf\n\t"
    "v_mul_f32_dpp %3, %4, %8 row_ror:3 row_mask:0xf bank_mask:0xf\n\t"
    "v_fmac_f32_dpp %0, %4, %9 row_ror:4 row_mask:0xf bank_mask:0xf\n\t"
    "v_fmac_f32_dpp %1, %4, %10 row_ror:5 row_mask:0xf bank_mask:0xf\n\t"
    "v_fmac_f32_dpp %2, %4, %11 row_ror:6 row_mask:0xf bank_mask:0xf\n\t"
    "v_fmac_f32_dpp %3, %4, %12 row_ror:7 row_mask:0xf bank_mask:0xf\n\t"
    "v_fmac_f32_dpp %0, %4, %13 row_ror:8 row_mask:0xf bank_mask:0xf\n\t"
    "v_fmac_f32_dpp %1, %4, %14 row_ror:9 row_mask:0xf bank_mask:0xf\n\t"
    "v_fmac_f32_dpp %2, %4, %15 row_ror:10 row_mask:0xf bank_mask:0xf\n\t"
    "v_fmac_f32_dpp %3, %4, %16 row_ror:11 row_mask:0xf bank_mask:0xf\n\t"
    "v_fmac_f32_dpp %0, %4, %17 row_ror:12 row_mask:0xf bank_mask:0xf\n\t"
    "v_fmac_f32_dpp %1, %4, %18 row_ror:13 row_mask:0xf bank_mask:0xf\n\t"
    "v_fmac_f32_dpp %2, %4, %19 row_ror:14 row_mask:0xf bank_mask:0xf\n\t"
    "v_fmac_f32_dpp %3, %4, %20 row_ror:15 row_mask:0xf bank_mask:0xf"
    : "+v"(a0), "+v"(a1), "+v"(a2), "+v"(a3)
    : "v"(p),
      "v"(E[0]),  "v"(E[1]),  "v"(E[2]),  "v"(E[3]),
      "v"(E[4]),  "v"(E[5]),  "v"(E[6]),  "v"(E[7]),
      "v"(E[8]),  "v"(E[9]),  "v"(E[10]), "v"(E[11]),
      "v"(E[12]), "v"(E[13]), "v"(E[14]), "v"(E[15]));
  return (a0 + a1) + (a2 + a3);
}

__global__ void zero_out_k(float* out) {
  if (threadIdx.x < 2) out[threadIdx.x] = 0.0f;
}

// counting sort by descending length (R22-validated LPT)
__global__ __launch_bounds__(1024)
void sort_perm_k(const int* __restrict__ lens, int* __restrict__ perm) {
  __shared__ int h0[1024], h1[1024];
  const int tid = threadIdx.x;
  h0[tid] = 0;
  __syncthreads();
  for (int i = tid; i < NB; i += 1024) atomicAdd(&h0[1024 - lens[i]], 1);
  __syncthreads();
  const int cnt = h0[tid];
  int* src = h0; int* dst = h1;
  for (int off = 1; off < 1024; off <<= 1) {
    dst[tid] = src[tid] + ((tid >= off) ? src[tid - off] : 0);
    __syncthreads();
    int* tmp = src; src = dst; dst = tmp;
  }
  const int excl = src[tid] - cnt;
  __syncthreads();
  dst[tid] = excl;
  __syncthreads();
  for (int i = tid; i < NB; i += 1024) {
    const int key = 1024 - lens[i];
    const int pos = atomicAdd(&dst[key], 1);
    perm[pos] = i;
  }
}

// 4 waves/block hybrid: w0 = fwd vector chain [1,c1] (R23), w1/w2 = matrix
// operators for (c1,c2], (c2,c3] (R18 cadence-1 MSTEP, verbatim), w3 = bwd
// vector chain (c3,len-1] (R23). Junction: alpha through M2,M3 (R18 phase-2).
__global__ __launch_bounds__(256, 4)
void crf_fwd(const float* __restrict__ scores, const float* __restrict__ trans,
             const int* __restrict__ lens, const int* __restrict__ tags,
             const int* __restrict__ perm, float* __restrict__ out)
{
  constexpr float LOG2E = 1.4426950408889634f;
  constexpr float LN2   = 0.6931471805599453f;
  __shared__ float Tld[NL * NL];
  __shared__ alignas(16) unsigned short Mb[2][NL * NL];
  __shared__ float Xls[2][NL];
  __shared__ float slotm[64];

  const int b    = perm ? perm[blockIdx.x] : blockIdx.x;
  const int tid  = threadIdx.x;
  const int w    = tid >> 6;
  const int lane = tid & 63;
  const int len  = lens[b];
  const int nsteps = len - 1;
  const int Lm = (3 * nsteps) / 19;             // per matrix segment (65:30 balance)
  const int c1 = (nsteps - 2 * Lm + 1) >> 1;    // fwd vector covers [1, c1]
  const int c2 = c1 + Lm;
  const int c3 = c2 + Lm;
  const int nBw = nsteps - c3;                  // bwd vector covers (c3, len-1]
  const int r = lane >> 4, c = lane & 15;
  const int labA = c + ((r & 1) << 4);
  const int col  = lane & 31;
  const int half = lane >> 5;

  const int p16 = plswap16_partner(lane);
  const bool plOK = ((p16 & 15) == c) && ((((p16 >> 4) ^ r) & 1) == 1);
  const int pmax = (lane > p16) ? lane : p16;
  const int labB = plOK ? (c + ((pmax >= 48) ? 16 : 0))
                        : (c + (((r >> 1) & 1) << 4));

  // runtime probe of permlane32_swap direction (R16-validated)
  unsigned px = half ? 200u : 100u, py = half ? 400u : 300u;
  plswap32_pair(px, py);
  const bool dirC1 = (__builtin_amdgcn_readfirstlane(px) == 100u);

  const float* sbf = scores + (size_t)b * (NS * NL);

  for (int k2 = tid; k2 < NL * NL; k2 += 256) Tld[k2] = trans[k2] * LOG2E;
  __syncthreads();

#define COMB16(S) (plOK ? plswap16_sum(S) : ((S) + __shfl_xor((S), 16)))
#define LDROW(DST, ROW, LAB) do { \
    int r_ = (ROW); r_ = r_ < 0 ? 0 : r_; r_ = r_ > len - 1 ? len - 1 : r_; \
    DST = sbf[(size_t)r_ * NL + (LAB)]; \
  } while (0)
#define RENU do { \
    const int eb_ = __builtin_amdgcn_readfirstlane(__float_as_int(u)); \
    const int ex_ = (eb_ >> 23) - 127; \
    ls += (float)ex_; \
    u *= __int_as_float((127 - ex_) << 23); \
  } while (0)

  float u = 1.0f, ls = 0.0f;
  bool endB = false;

  if (w == 0) {
    // ---------------- forward vector chain: steps 1..c1 (R23-validated) ----------------
    float EA[16], EB[16];
#define CFA(K) EA[K] = fexp2(Tld[roti<K>(labA) * NL + labB]);
#define CFB(K) EB[K] = fexp2(Tld[roti<K>(labB) * NL + labA]);
    CFA(0)  CFA(1)  CFA(2)  CFA(3)  CFA(4)  CFA(5)  CFA(6)  CFA(7)
    CFA(8)  CFA(9)  CFA(10) CFA(11) CFA(12) CFA(13) CFA(14) CFA(15)
    CFB(0)  CFB(1)  CFB(2)  CFB(3)  CFB(4)  CFB(5)  CFB(6)  CFB(7)
    CFB(8)  CFB(9)  CFB(10) CFB(11) CFB(12) CFB(13) CFB(14) CFB(15)
#undef CFA
#undef CFB
    float a0 = Tld[31 * NL + labA] + LOG2E * sbf[labA];
    ls = __int_as_float(__builtin_amdgcn_readfirstlane(__float_as_int(a0)));
    u = fexp2(a0 - ls);

    float P0, P1, P2, P3, Q0, Q1, Q2, Q3;
    int t = 1;
    LDROW(P0, 1, labB); LDROW(P1, 2, labA); LDROW(P2, 3, labB); LDROW(P3, 4, labA);
    LDROW(Q0, 5, labB); LDROW(Q1, 6, labA); LDROW(Q2, 7, labB); LDROW(Q3, 8, labA);

#define FBODY(B0, B1, B2, B3) do { \
    RENU; \
    const float w0 = fexp2(B0 * LOG2E); \
    const float w1 = fexp2(B1 * LOG2E); \
    const float w2 = fexp2(B2 * LOG2E); \
    const float w3 = fexp2(B3 * LOG2E); \
    LDROW(B0, t + 8,  labB); LDROW(B1, t + 9,  labA); \
    LDROW(B2, t + 10, labB); LDROW(B3, t + 11, labA); \
    u = COMB16(tree16f(u, EA)) * w0; \
    u = plswap32_sum(tree16f(u, EB)) * w1; \
    u = COMB16(tree16f(u, EA)) * w2; \
    u = plswap32_sum(tree16f(u, EB)) * w3; \
  } while (0)

    while (t + 7 <= c1) {
      FBODY(P0, P1, P2, P3); t += 4;
      FBODY(Q0, Q1, Q2, Q3); t += 4;
    }
    if (t + 3 <= c1) { FBODY(P0, P1, P2, P3); t += 4; }
    while (t <= c1) {
      if ((t & 3) == 1) RENU;
      if (t & 1) {
        float e; LDROW(e, t, labB);
        u = COMB16(tree16f(u, EA)) * fexp2(e * LOG2E);
        endB = true;
      } else {
        float e; LDROW(e, t, labA);
        u = plswap32_sum(tree16f(u, EB)) * fexp2(e * LOG2E);
        endB = false;
      }
      t++;
    }
#undef FBODY
  } else if (w == 3) {
    // ---------------- backward vector chain: steps len-1 down to c3+1 (R23) ----------------
    float EA[16], EB[16];
#define CBA(K) EA[K] = fexp2(Tld[labB * NL + roti<K>(labA)]);
#define CBB(K) EB[K] = fexp2(Tld[labA * NL + roti<K>(labB)]);
    CBA(0)  CBA(1)  CBA(2)  CBA(3)  CBA(4)  CBA(5)  CBA(6)  CBA(7)
    CBA(8)  CBA(9)  CBA(10) CBA(11) CBA(12) CBA(13) CBA(14) CBA(15)
    CBB(0)  CBB(1)  CBB(2)  CBB(3)  CBB(4)  CBB(5)  CBB(6)  CBB(7)
    CBB(8)  CBB(9)  CBB(10) CBB(11) CBB(12) CBB(13) CBB(14) CBB(15)
#undef CBA
#undef CBB
    float a0 = Tld[labA * NL + 30];
    ls = __int_as_float(__builtin_amdgcn_readfirstlane(__float_as_int(a0)));
    u = fexp2(a0 - ls);

    float P0, P1, P2, P3, Q0, Q1, Q2, Q3;
    int k = 0;
    LDROW(P0, len - 1, labA); LDROW(P1, len - 2, labB);
    LDROW(P2, len - 3, labA); LDROW(P3, len - 4, labB);
    LDROW(Q0, len - 5, labA); LDROW(Q1, len - 6, labB);
    LDROW(Q2, len - 7, labA); LDROW(Q3, len - 8, labB);

#define BBODY(B0, B1, B2, B3) do { \
    RENU; \
    const float w0 = fexp2(B0 * LOG2E); \
    const float w1 = fexp2(B1 * LOG2E); \
    const float w2 = fexp2(B2 * LOG2E); \
    const float w3 = fexp2(B3 * LOG2E); \
    LDROW(B0, len - 1 - k - 8,  labA); LDROW(B1, len - 2 - k - 8,  labB); \
    LDROW(B2, len - 3 - k - 8,  labA); LDROW(B3, len - 4 - k - 8,  labB); \
    u = COMB16(tree16f(u * w0, EA)); \
    u = plswap32_sum(tree16f(u * w1, EB)); \
    u = COMB16(tree16f(u * w2, EA)); \
    u = plswap32_sum(tree16f(u * w3, EB)); \
  } while (0)

    while (k + 7 < nBw) {
      BBODY(P0, P1, P2, P3); k += 4;
      BBODY(Q0, Q1, Q2, Q3); k += 4;
    }
    if (k + 3 < nBw) { BBODY(P0, P1, P2, P3); k += 4; }
    while (k < nBw) {
      if ((k & 3) == 0) RENU;
      if (!(k & 1)) {
        float e; LDROW(e, len - 1 - k, labA);
        u = COMB16(tree16f(u * fexp2(e * LOG2E), EA));
        endB = true;
      } else {
        float e; LDROW(e, len - 1 - k, labB);
        u = plswap32_sum(tree16f(u * fexp2(e * LOG2E), EB));
        endB = false;
      }
      k++;
    }
#undef BBODY
    // beta_{c3} done: publish to slot (absolute label index -> layout-agnostic)
    slotm[32 + (endB ? labB : labA)] = ls + flog2(u);
  } else {
    // ---------------- matrix wave (w=1,2): R18 cadence-1 machinery, verbatim ----------------
    const int mi = w - 1;
    const int t0 = (w == 1 ? c1 + 1 : c2 + 1);
    const int v  = Lm;

    if (v == 0) {
      unsigned* mw = (unsigned*)&Mb[mi][0];
      #pragma unroll
      for (int q = 0; q < 8; ++q) mw[lane + 64 * q] = 0u;
      asm volatile("s_waitcnt lgkmcnt(0)" ::: "memory");
      if (lane < 32) { Mb[mi][lane * NL + lane] = 0x3F80; Xls[mi][lane] = 0.0f; }
    } else {
      float EAb1[8], EAb2[8];
      #pragma unroll
      for (int p = 0; p < 8; ++p) {
        EAb1[p] = fexp2(Tld[(8 * half + p) * NL + col]);
        EAb2[p] = fexp2(Tld[(16 + 8 * half + p) * NL + col]);
      }
      f32x16 acc;
      #pragma unroll
      for (int i = 0; i < 16; ++i) {
        const int row = (i & 3) + 8 * (i >> 2) + 4 * half;
        acc[i] = (row == col) ? 1.0f : 0.0f;
      }
      float Xw = 0.0f;

#define MLDW(T) sbf[(size_t)(((T) > len - 1) ? (len - 1) : (T)) * NL + col]
      float er0 = MLDW(t0 + 0), er1 = MLDW(t0 + 1), er2 = MLDW(t0 + 2), er3 = MLDW(t0 + 3);
      float er4 = MLDW(t0 + 4), er5 = MLDW(t0 + 5), er6 = MLDW(t0 + 6), er7 = MLDW(t0 + 7);

#define MSTEP(EQ) do { \
    const float ws_ = fexp2((EQ) * LOG2E); \
    FragU a1_, a2_, b1_, b2_; \
    _Pragma("unroll") \
    for (int p_ = 0; p_ < 4; ++p_) { \
      a1_.u[p_] = cvtpk(EAb1[2 * p_] * ws_, EAb1[2 * p_ + 1] * ws_); \
      a2_.u[p_] = cvtpk(EAb2[2 * p_] * ws_, EAb2[2 * p_ + 1] * ws_); \
    } \
    unsigned pk0_ = cvtpk(acc[0],  acc[1]),  pk1_ = cvtpk(acc[2],  acc[3]); \
    unsigned pk2_ = cvtpk(acc[4],  acc[5]),  pk3_ = cvtpk(acc[6],  acc[7]); \
    unsigned pk4_ = cvtpk(acc[8],  acc[9]),  pk5_ = cvtpk(acc[10], acc[11]); \
    unsigned pk6_ = cvtpk(acc[12], acc[13]), pk7_ = cvtpk(acc[14], acc[15]); \
    if (dirC1) { \
      plswap32_pair(pk0_, pk2_); b1_.u[0] = pk0_; b1_.u[2] = pk2_; \
      plswap32_pair(pk1_, pk3_); b1_.u[1] = pk1_; b1_.u[3] = pk3_; \
      plswap32_pair(pk4_, pk6_); b2_.u[0] = pk4_; b2_.u[2] = pk6_; \
      plswap32_pair(pk5_, pk7_); b2_.u[1] = pk5_; b2_.u[3] = pk7_; \
    } else { \
      plswap32_pair(pk2_, pk0_); b1_.u[2] = pk2_; b1_.u[0] = pk0_; \
      plswap32_pair(pk3_, pk1_); b1_.u[3] = pk3_; b1_.u[1] = pk1_; \
      plswap32_pair(pk6_, pk4_); b2_.u[2] = pk6_; b2_.u[0] = pk4_; \
      plswap32_pair(pk7_, pk5_); b2_.u[3] = pk7_; b2_.u[1] = pk5_; \
    } \
    f32x16 z_; \
    _Pragma("unroll") \
    for (int i_ = 0; i_ < 16; ++i_) z_[i_] = 0.0f; \
    z_  = __builtin_amdgcn_mfma_f32_32x32x16_bf16(a1_.v, b1_.v, z_, 0, 0, 0); \
    acc = __builtin_amdgcn_mfma_f32_32x32x16_bf16(a2_.v, b2_.v, z_, 0, 0, 0); \
    float mx_ = fmaxf(fmaxf(fmaxf(acc[0], acc[1]), fmaxf(acc[2], acc[3])), \
                      fmaxf(fmaxf(acc[4], acc[5]), fmaxf(acc[6], acc[7]))); \
    mx_ = fmaxf(mx_, fmaxf(fmaxf(fmaxf(acc[8], acc[9]), fmaxf(acc[10], acc[11])), \
                           fmaxf(fmaxf(acc[12], acc[13]), fmaxf(acc[14], acc[15])))); \
    mx_ = plswap32_max(mx_); \
    const int ex_ = (__float_as_int(mx_) >> 23) - 127; \
    const float rs_ = __int_as_float((127 - ex_) << 23); \
    _Pragma("unroll") \
    for (int i_ = 0; i_ < 16; ++i_) acc[i_] *= rs_; \
    Xw += (float)ex_; \
  } while (0)

      int sg = 0;
      while (sg + 8 <= v) {
        MSTEP(er0); er0 = MLDW(t0 + sg + 8);
        MSTEP(er1); er1 = MLDW(t0 + sg + 9);
        MSTEP(er2); er2 = MLDW(t0 + sg + 10);
        MSTEP(er3); er3 = MLDW(t0 + sg + 11);
        MSTEP(er4); er4 = MLDW(t0 + sg + 12);
        MSTEP(er5); er5 = MLDW(t0 + sg + 13);
        MSTEP(er6); er6 = MLDW(t0 + sg + 14);
        MSTEP(er7); er7 = MLDW(t0 + sg + 15);
        sg += 8;
      }
      if (sg + 0 < v) MSTEP(er0);
      if (sg + 1 < v) MSTEP(er1);
      if (sg + 2 < v) MSTEP(er2);
      if (sg + 3 < v) MSTEP(er3);
      if (sg + 4 < v) MSTEP(er4);
      if (sg + 5 < v) MSTEP(er5);
      if (sg + 6 < v) MSTEP(er6);
      if (sg + 7 < v) MSTEP(er7);

      {
        unsigned* mw32 = (unsigned*)&Mb[mi][0];
        #pragma unroll
        for (int j = 0; j < 8; ++j) {
          const int row0 = (2 * j & 3) + 8 * (2 * j >> 2) + 4 * half;
          mw32[(col * NL + row0) >> 1] = cvtpk(acc[2 * j], acc[2 * j + 1]);
        }
      }
      if (lane < 32) Xls[mi][col] = Xw;
#undef MSTEP
#undef MLDW
    }
  }

  __syncthreads();

  if (w == 0) {
    // ---------------- junction: alpha through M2, M3 (R18 phase-2, verbatim) ----------------
    bool curB = endB;
    for (int cdx = 0; cdx < 2; ++cdx) {
      const int held = curB ? labB : labA;
      const int outl = curB ? labA : labB;
      const float dX = Xls[cdx][held];
      const float X0 = __int_as_float(__builtin_amdgcn_readfirstlane(__float_as_int(dX)));
      u *= fexp2(fminf(dX - X0, 120.0f));
      ls += X0;
      RENU;
      float Ec[16];
#define LDE(K) Ec[K] = bf2f(Mb[cdx][roti<K>(held) * NL + outl]);
      LDE(0)  LDE(1)  LDE(2)  LDE(3)  LDE(4)  LDE(5)  LDE(6)  LDE(7)
      LDE(8)  LDE(9)  LDE(10) LDE(11) LDE(12) LDE(13) LDE(14) LDE(15)
#undef LDE
      const float s16 = tree16f(u, Ec);
      u = (!curB) ? COMB16(s16) : plswap32_sum(s16);
      RENU;
      curB = !curB;
    }
    slotm[curB ? labB : labA] = ls + flog2(u);
    asm volatile("s_waitcnt lgkmcnt(0)" ::: "memory");

    // Z = ln2 * LSE2_j(alphalog[j] + betalog[j])  (beta written pre-barrier by w3)
    float v2 = (lane < 32) ? (slotm[lane] + slotm[32 + lane]) : -3.0e38f;
    float mm = v2;
    #pragma unroll
    for (int ww = 32; ww; ww >>= 1) mm = fmaxf(mm, __shfl_xor(mm, ww));
    float ssum = fexp2(v2 - mm);
    #pragma unroll
    for (int ww = 32; ww; ww >>= 1) ssum += __shfl_xor(ssum, ww);
    if (lane == 0) atomicAdd(out + 0, LN2 * (mm + flog2(ssum)));
  } else if (w == 1) {
    // ---------------- labeled score (R13-validated) ----------------
    const int* tb = tags + (size_t)b * NS;
    float lab = 0.0f;
    if (lane == 0) {
      const int tg0 = tb[0];
      lab += Tld[31 * NL + tg0] + LOG2E * sbf[tg0];
      const int tgl = tb[len - 1];
      lab += Tld[tgl * NL + 30];
    }
    for (int t2 = 1 + lane; t2 < len; t2 += 64) {
      const int tp = tb[t2 - 1];
      const int tg = tb[t2];
      lab += Tld[tp * NL + tg] + LOG2E * sbf[(size_t)t2 * NL + tg];
    }
    #pragma unroll
    for (int ww = 32; ww; ww >>= 1) lab += __shfl_xor(lab, ww);
    if (lane == 0) atomicAdd(out + 1, LN2 * lab);
  }
#undef COMB16
#undef LDROW
#undef RENU
}

extern "C" void kernel_launch(void* const* d_in, const int* in_sizes, int n_in,
                              void* d_out, int out_size, void* d_ws, size_t ws_size,
                              hipStream_t stream) {
  const float* scores = (const float*)d_in[0];
  const float* trans  = (const float*)d_in[1];
  const int*   lens   = (const int*)d_in[2];
  const int*   tags   = (const int*)d_in[3];
  float* out = (float*)d_out;

  int* perm = (ws_size >= NB * sizeof(int)) ? (int*)d_ws : nullptr;

  zero_out_k<<<1, 64, 0, stream>>>(out);
  if (perm) sort_perm_k<<<1, 1024, 0, stream>>>(lens, perm);
  crf_fwd<<<NB, 256, 0, stream>>>(scores, trans, lens, tags, perm, out);
}

// Round 25
// 123.270 us; speedup vs baseline: 1.0722x; 1.0722x over previous
//
#include <hip/hip_runtime.h>

#define NB 2048
#define NS 1024
#define NL 32

typedef short bf16x8 __attribute__((ext_vector_type(8)));
typedef float f32x16 __attribute__((ext_vector_type(16)));
union FragU { unsigned u[4]; bf16x8 v; };

static __device__ __forceinline__ float fexp2(float x) {
#if __has_builtin(__builtin_amdgcn_exp2f)
  return __builtin_amdgcn_exp2f(x);
#else
  float r; asm("v_exp_f32 %0, %1" : "=v"(r) : "v"(x)); return r;
#endif
}
static __device__ __forceinline__ float flog2(float x) {
#if __has_builtin(__builtin_amdgcn_logf)
  return __builtin_amdgcn_logf(x);
#else
  float r; asm("v_log_f32 %0, %1" : "=v"(r) : "v"(x)); return r;
#endif
}

template<int K>
static __device__ __forceinline__ int roti(int x) {
  if constexpr (K == 0) return x;
  else return __builtin_amdgcn_update_dpp(0, x, 0x120 | K, 0xf, 0xf, true); // row_ror:K
}

// permlane swaps with s_nop hazard guards (R10-validated pattern)
static __device__ __forceinline__ void plswap32_pair(unsigned &x, unsigned &y) {
  asm volatile("s_nop 1\n\tv_permlane32_swap_b32 %0, %1\n\ts_nop 1"
               : "+v"(x), "+v"(y));
}
static __device__ __forceinline__ float plswap16_sum(float part) {
  float x, y;
  asm volatile("v_mov_b32 %0, %2\n\tv_mov_b32 %1, %2\n\ts_nop 1\n\t"
               "v_permlane16_swap_b32 %0, %1\n\ts_nop 1"
               : "=&v"(x), "=&v"(y) : "v"(part));
  return x + y;
}
static __device__ __forceinline__ float plswap32_sum(float part) {
  float x, y;
  asm volatile("v_mov_b32 %0, %2\n\tv_mov_b32 %1, %2\n\ts_nop 1\n\t"
               "v_permlane32_swap_b32 %0, %1\n\ts_nop 1"
               : "=&v"(x), "=&v"(y) : "v"(part));
  return x + y;
}
static __device__ __forceinline__ float plswap32_max(float part) {
  float x, y;
  asm volatile("v_mov_b32 %0, %2\n\tv_mov_b32 %1, %2\n\ts_nop 1\n\t"
               "v_permlane32_swap_b32 %0, %1\n\ts_nop 1"
               : "=&v"(x), "=&v"(y) : "v"(part));
  return fmaxf(x, y);
}
static __device__ __forceinline__ int plswap16_partner(int lane) {
  int x, y;
  asm volatile("v_mov_b32 %0, %2\n\tv_mov_b32 %1, %2\n\ts_nop 1\n\t"
               "v_permlane16_swap_b32 %0, %1\n\ts_nop 1"
               : "=&v"(x), "=&v"(y) : "v"(lane));
  return x + y - lane;
}

// pack two f32 -> bf16x2 (src0 -> lo)
static __device__ __forceinline__ unsigned cvtpk(float a, float b) {
  unsigned r;
  asm("v_cvt_pk_bf16_f32 %0, %1, %2" : "=v"(r) : "v"(a), "v"(b));
  return r;
}
static __device__ __forceinline__ float bf2f(unsigned short u) {
  return __int_as_float(((int)u) << 16);
}

// 16-term rotate/FMA tree, DPP-fused (R23-validated; same row_ror perm as roti<K>)
static __device__ __forceinline__ float tree16f(float p, const float* E) {
  float a0 = 0.0f, a1 = 0.0f, a2 = 0.0f, a3 = 0.0f;
  asm volatile(
    "s_nop 1\n\t"
    "v_mul_f32 %0, %4, %5\n\t"
    "v_mul_f32_dpp %1, %4, %6 row_ror:1 row_mask:0xf bank_mask:0xf\n\t"
    "v_mul_f32_dpp %2, %4, %7 row_ror:2 row_mask:0xf bank_mask:0xf\n\t"
    "v_mul_f32_dpp %3, %4, %8 row_ror:3 row_mask:0xf bank_mask:0xf\n\t"
    "v_fmac_f32_dpp %0, %4, %9 row_ror:4 row_mask:0xf bank_mask:0xf\n\t"
    "v_fmac_f32_dpp %1, %4, %10 row_ror:5 row_mask:0xf bank_mask:0xf\n\t"
    "v_fmac_f32_dpp %2, %4, %11 row_ror:6 row_mask:0xf bank_mask:0xf\n\t"
    "v_fmac_f32_dpp %3, %4, %12 row_ror:7 row_mask:0xf bank_mask:0xf\n\t"
    "v_fmac_f32_dpp %0, %4, %13 row_ror:8 row_mask:0xf bank_mask:0xf\n\t"
    "v_fmac_f32_dpp %1, %4, %14 row_ror:9 row_mask:0xf bank_mask:0xf\n\t"
    "v_fmac_f32_dpp %2, %4, %15 row_ror:10 row_mask:0xf bank_mask:0xf\n\t"
    "v_fmac_f32_dpp %3, %4, %16 row_ror:11 row_mask:0xf bank_mask:0xf\n\t"
    "v_fmac_f32_dpp %0, %4, %17 row_ror:12 row_mask:0xf bank_mask:0xf\n\t"
    "v_fmac_f32_dpp %1, %4, %18 row_ror:13 row_mask:0xf bank_mask:0xf\n\t"
    "v_fmac_f32_dpp %2, %4, %19 row_ror:14 row_mask:0xf bank_mask:0xf\n\t"
    "v_fmac_f32_dpp %3, %4, %20 row_ror:15 row_mask:0xf bank_mask:0xf"
    : "+v"(a0), "+v"(a1), "+v"(a2), "+v"(a3)
    : "v"(p),
      "v"(E[0]),  "v"(E[1]),  "v"(E[2]),  "v"(E[3]),
      "v"(E[4]),  "v"(E[5]),  "v"(E[6]),  "v"(E[7]),
      "v"(E[8]),  "v"(E[9]),  "v"(E[10]), "v"(E[11]),
      "v"(E[12]), "v"(E[13]), "v"(E[14]), "v"(E[15]));
  return (a0 + a1) + (a2 + a3);
}

__global__ void zero_out_k(float* out) {
  if (threadIdx.x < 2) out[threadIdx.x] = 0.0f;
}

// counting sort by descending length (R22-validated LPT)
__global__ __launch_bounds__(1024)
void sort_perm_k(const int* __restrict__ lens, int* __restrict__ perm) {
  __shared__ int h0[1024], h1[1024];
  const int tid = threadIdx.x;
  h0[tid] = 0;
  __syncthreads();
  for (int i = tid; i < NB; i += 1024) atomicAdd(&h0[1024 - lens[i]], 1);
  __syncthreads();
  const int cnt = h0[tid];
  int* src = h0; int* dst = h1;
  for (int off = 1; off < 1024; off <<= 1) {
    dst[tid] = src[tid] + ((tid >= off) ? src[tid - off] : 0);
    __syncthreads();
    int* tmp = src; src = dst; dst = tmp;
  }
  const int excl = src[tid] - cnt;
  __syncthreads();
  dst[tid] = excl;
  __syncthreads();
  for (int i = tid; i < NB; i += 1024) {
    const int key = 1024 - lens[i];
    const int pos = atomicAdd(&dst[key], 1);
    perm[pos] = i;
  }
}

// 4 waves/block hybrid (R24-validated machinery, rebalanced): Lm = nsteps/9
// (measured cm/cv ~= 3.5, so Lm = n*cv/(2(cm+cv)) ~= n/9; R24's 3n/19 made
// the matrix waves the critical path).
__global__ __launch_bounds__(256, 4)
void crf_fwd(const float* __restrict__ scores, const float* __restrict__ trans,
             const int* __restrict__ lens, const int* __restrict__ tags,
             const int* __restrict__ perm, float* __restrict__ out)
{
  constexpr float LOG2E = 1.4426950408889634f;
  constexpr float LN2   = 0.6931471805599453f;
  __shared__ float Tld[NL * NL];
  __shared__ alignas(16) unsigned short Mb[2][NL * NL];
  __shared__ float Xls[2][NL];
  __shared__ float slotm[64];

  const int b    = perm ? perm[blockIdx.x] : blockIdx.x;
  const int tid  = threadIdx.x;
  const int w    = tid >> 6;
  const int lane = tid & 63;
  const int len  = lens[b];
  const int nsteps = len - 1;
  const int Lm = nsteps / 9;                    // rebalanced (was 3*nsteps/19)
  const int c1 = (nsteps - 2 * Lm + 1) >> 1;    // fwd vector covers [1, c1]
  const int c2 = c1 + Lm;
  const int c3 = c2 + Lm;
  const int nBw = nsteps - c3;                  // bwd vector covers (c3, len-1]
  const int r = lane >> 4, c = lane & 15;
  const int labA = c + ((r & 1) << 4);
  const int col  = lane & 31;
  const int half = lane >> 5;

  const int p16 = plswap16_partner(lane);
  const bool plOK = ((p16 & 15) == c) && ((((p16 >> 4) ^ r) & 1) == 1);
  const int pmax = (lane > p16) ? lane : p16;
  const int labB = plOK ? (c + ((pmax >= 48) ? 16 : 0))
                        : (c + (((r >> 1) & 1) << 4));

  // runtime probe of permlane32_swap direction (R16-validated)
  unsigned px = half ? 200u : 100u, py = half ? 400u : 300u;
  plswap32_pair(px, py);
  const bool dirC1 = (__builtin_amdgcn_readfirstlane(px) == 100u);

  const float* sbf = scores + (size_t)b * (NS * NL);

  for (int k2 = tid; k2 < NL * NL; k2 += 256) Tld[k2] = trans[k2] * LOG2E;
  __syncthreads();

#define COMB16(S) (plOK ? plswap16_sum(S) : ((S) + __shfl_xor((S), 16)))
#define LDROW(DST, ROW, LAB) do { \
    int r_ = (ROW); r_ = r_ < 0 ? 0 : r_; r_ = r_ > len - 1 ? len - 1 : r_; \
    DST = sbf[(size_t)r_ * NL + (LAB)]; \
  } while (0)
#define RENU do { \
    const int eb_ = __builtin_amdgcn_readfirstlane(__float_as_int(u)); \
    const int ex_ = (eb_ >> 23) - 127; \
    ls += (float)ex_; \
    u *= __int_as_float((127 - ex_) << 23); \
  } while (0)

  float u = 1.0f, ls = 0.0f;
  bool endB = false;

  if (w == 0) {
    // ---------------- forward vector chain: steps 1..c1 (R23-validated) ----------------
    float EA[16], EB[16];
#define CFA(K) EA[K] = fexp2(Tld[roti<K>(labA) * NL + labB]);
#define CFB(K) EB[K] = fexp2(Tld[roti<K>(labB) * NL + labA]);
    CFA(0)  CFA(1)  CFA(2)  CFA(3)  CFA(4)  CFA(5)  CFA(6)  CFA(7)
    CFA(8)  CFA(9)  CFA(10) CFA(11) CFA(12) CFA(13) CFA(14) CFA(15)
    CFB(0)  CFB(1)  CFB(2)  CFB(3)  CFB(4)  CFB(5)  CFB(6)  CFB(7)
    CFB(8)  CFB(9)  CFB(10) CFB(11) CFB(12) CFB(13) CFB(14) CFB(15)
#undef CFA
#undef CFB
    float a0 = Tld[31 * NL + labA] + LOG2E * sbf[labA];
    ls = __int_as_float(__builtin_amdgcn_readfirstlane(__float_as_int(a0)));
    u = fexp2(a0 - ls);

    float P0, P1, P2, P3, Q0, Q1, Q2, Q3;
    int t = 1;
    LDROW(P0, 1, labB); LDROW(P1, 2, labA); LDROW(P2, 3, labB); LDROW(P3, 4, labA);
    LDROW(Q0, 5, labB); LDROW(Q1, 6, labA); LDROW(Q2, 7, labB); LDROW(Q3, 8, labA);

#define FBODY(B0, B1, B2, B3) do { \
    RENU; \
    const float w0 = fexp2(B0 * LOG2E); \
    const float w1 = fexp2(B1 * LOG2E); \
    const float w2 = fexp2(B2 * LOG2E); \
    const float w3 = fexp2(B3 * LOG2E); \
    LDROW(B0, t + 8,  labB); LDROW(B1, t + 9,  labA); \
    LDROW(B2, t + 10, labB); LDROW(B3, t + 11, labA); \
    u = COMB16(tree16f(u, EA)) * w0; \
    u = plswap32_sum(tree16f(u, EB)) * w1; \
    u = COMB16(tree16f(u, EA)) * w2; \
    u = plswap32_sum(tree16f(u, EB)) * w3; \
  } while (0)

    while (t + 7 <= c1) {
      FBODY(P0, P1, P2, P3); t += 4;
      FBODY(Q0, Q1, Q2, Q3); t += 4;
    }
    if (t + 3 <= c1) { FBODY(P0, P1, P2, P3); t += 4; }
    while (t <= c1) {
      if ((t & 3) == 1) RENU;
      if (t & 1) {
        float e; LDROW(e, t, labB);
        u = COMB16(tree16f(u, EA)) * fexp2(e * LOG2E);
        endB = true;
      } else {
        float e; LDROW(e, t, labA);
        u = plswap32_sum(tree16f(u, EB)) * fexp2(e * LOG2E);
        endB = false;
      }
      t++;
    }
#undef FBODY
  } else if (w == 3) {
    // ---------------- backward vector chain: steps len-1 down to c3+1 (R23) ----------------
    float EA[16], EB[16];
#define CBA(K) EA[K] = fexp2(Tld[labB * NL + roti<K>(labA)]);
#define CBB(K) EB[K] = fexp2(Tld[labA * NL + roti<K>(labB)]);
    CBA(0)  CBA(1)  CBA(2)  CBA(3)  CBA(4)  CBA(5)  CBA(6)  CBA(7)
    CBA(8)  CBA(9)  CBA(10) CBA(11) CBA(12) CBA(13) CBA(14) CBA(15)
    CBB(0)  CBB(1)  CBB(2)  CBB(3)  CBB(4)  CBB(5)  CBB(6)  CBB(7)
    CBB(8)  CBB(9)  CBB(10) CBB(11) CBB(12) CBB(13) CBB(14) CBB(15)
#undef CBA
#undef CBB
    float a0 = Tld[labA * NL + 30];
    ls = __int_as_float(__builtin_amdgcn_readfirstlane(__float_as_int(a0)));
    u = fexp2(a0 - ls);

    float P0, P1, P2, P3, Q0, Q1, Q2, Q3;
    int k = 0;
    LDROW(P0, len - 1, labA); LDROW(P1, len - 2, labB);
    LDROW(P2, len - 3, labA); LDROW(P3, len - 4, labB);
    LDROW(Q0, len - 5, labA); LDROW(Q1, len - 6, labB);
    LDROW(Q2, len - 7, labA); LDROW(Q3, len - 8, labB);

#define BBODY(B0, B1, B2, B3) do { \
    RENU; \
    const float w0 = fexp2(B0 * LOG2E); \
    const float w1 = fexp2(B1 * LOG2E); \
    const float w2 = fexp2(B2 * LOG2E); \
    const float w3 = fexp2(B3 * LOG2E); \
    LDROW(B0, len - 1 - k - 8,  labA); LDROW(B1, len - 2 - k - 8,  labB); \
    LDROW(B2, len - 3 - k - 8,  labA); LDROW(B3, len - 4 - k - 8,  labB); \
    u = COMB16(tree16f(u * w0, EA)); \
    u = plswap32_sum(tree16f(u * w1, EB)); \
    u = COMB16(tree16f(u * w2, EA)); \
    u = plswap32_sum(tree16f(u * w3, EB)); \
  } while (0)

    while (k + 7 < nBw) {
      BBODY(P0, P1, P2, P3); k += 4;
      BBODY(Q0, Q1, Q2, Q3); k += 4;
    }
    if (k + 3 < nBw) { BBODY(P0, P1, P2, P3); k += 4; }
    while (k < nBw) {
      if ((k & 3) == 0) RENU;
      if (!(k & 1)) {
        float e; LDROW(e, len - 1 - k, labA);
        u = COMB16(tree16f(u * fexp2(e * LOG2E), EA));
        endB = true;
      } else {
        float e; LDROW(e, len - 1 - k, labB);
        u = plswap32_sum(tree16f(u * fexp2(e * LOG2E), EB));
        endB = false;
      }
      k++;
    }
#undef BBODY
    // beta_{c3} done: publish to slot (absolute label index -> layout-agnostic)
    slotm[32 + (endB ? labB : labA)] = ls + flog2(u);
  } else {
    // ---------------- matrix wave (w=1,2): R18 cadence-1 machinery, verbatim ----------------
    const int mi = w - 1;
    const int t0 = (w == 1 ? c1 + 1 : c2 + 1);
    const int v  = Lm;

    if (v == 0) {
      unsigned* mw = (unsigned*)&Mb[mi][0];
      #pragma unroll
      for (int q = 0; q < 8; ++q) mw[lane + 64 * q] = 0u;
      asm volatile("s_waitcnt lgkmcnt(0)" ::: "memory");
      if (lane < 32) { Mb[mi][lane * NL + lane] = 0x3F80; Xls[mi][lane] = 0.0f; }
    } else {
      float EAb1[8], EAb2[8];
      #pragma unroll
      for (int p = 0; p < 8; ++p) {
        EAb1[p] = fexp2(Tld[(8 * half + p) * NL + col]);
        EAb2[p] = fexp2(Tld[(16 + 8 * half + p) * NL + col]);
      }
      f32x16 acc;
      #pragma unroll
      for (int i = 0; i < 16; ++i) {
        const int row = (i & 3) + 8 * (i >> 2) + 4 * half;
        acc[i] = (row == col) ? 1.0f : 0.0f;
      }
      float Xw = 0.0f;

#define MLDW(T) sbf[(size_t)(((T) > len - 1) ? (len - 1) : (T)) * NL + col]
      float er0 = MLDW(t0 + 0), er1 = MLDW(t0 + 1), er2 = MLDW(t0 + 2), er3 = MLDW(t0 + 3);
      float er4 = MLDW(t0 + 4), er5 = MLDW(t0 + 5), er6 = MLDW(t0 + 6), er7 = MLDW(t0 + 7);

#define MSTEP(EQ) do { \
    const float ws_ = fexp2((EQ) * LOG2E); \
    FragU a1_, a2_, b1_, b2_; \
    _Pragma("unroll") \
    for (int p_ = 0; p_ < 4; ++p_) { \
      a1_.u[p_] = cvtpk(EAb1[2 * p_] * ws_, EAb1[2 * p_ + 1] * ws_); \
      a2_.u[p_] = cvtpk(EAb2[2 * p_] * ws_, EAb2[2 * p_ + 1] * ws_); \
    } \
    unsigned pk0_ = cvtpk(acc[0],  acc[1]),  pk1_ = cvtpk(acc[2],  acc[3]); \
    unsigned pk2_ = cvtpk(acc[4],  acc[5]),  pk3_ = cvtpk(acc[6],  acc[7]); \
    unsigned pk4_ = cvtpk(acc[8],  acc[9]),  pk5_ = cvtpk(acc[10], acc[11]); \
    unsigned pk6_ = cvtpk(acc[12], acc[13]), pk7_ = cvtpk(acc[14], acc[15]); \
    if (dirC1) { \
      plswap32_pair(pk0_, pk2_); b1_.u[0] = pk0_; b1_.u[2] = pk2_; \
      plswap32_pair(pk1_, pk3_); b1_.u[1] = pk1_; b1_.u[3] = pk3_; \
      plswap32_pair(pk4_, pk6_); b2_.u[0] = pk4_; b2_.u[2] = pk6_; \
      plswap32_pair(pk5_, pk7_); b2_.u[1] = pk5_; b2_.u[3] = pk7_; \
    } else { \
      plswap32_pair(pk2_, pk0_); b1_.u[2] = pk2_; b1_.u[0] = pk0_; \
      plswap32_pair(pk3_, pk1_); b1_.u[3] = pk3_; b1_.u[1] = pk1_; \
      plswap32_pair(pk6_, pk4_); b2_.u[2] = pk6_; b2_.u[0] = pk4_; \
      plswap32_pair(pk7_, pk5_); b2_.u[3] = pk7_; b2_.u[1] = pk5_; \
    } \
    f32x16 z_; \
    _Pragma("unroll") \
    for (int i_ = 0; i_ < 16; ++i_) z_[i_] = 0.0f; \
    z_  = __builtin_amdgcn_mfma_f32_32x32x16_bf16(a1_.v, b1_.v, z_, 0, 0, 0); \
    acc = __builtin_amdgcn_mfma_f32_32x32x16_bf16(a2_.v, b2_.v, z_, 0, 0, 0); \
    float mx_ = fmaxf(fmaxf(fmaxf(acc[0], acc[1]), fmaxf(acc[2], acc[3])), \
                      fmaxf(fmaxf(acc[4], acc[5]), fmaxf(acc[6], acc[7]))); \
    mx_ = fmaxf(mx_, fmaxf(fmaxf(fmaxf(acc[8], acc[9]), fmaxf(acc[10], acc[11])), \
                           fmaxf(fmaxf(acc[12], acc[13]), fmaxf(acc[14], acc[15])))); \
    mx_ = plswap32_max(mx_); \
    const int ex_ = (__float_as_int(mx_) >> 23) - 127; \
    const float rs_ = __int_as_float((127 - ex_) << 23); \
    _Pragma("unroll") \
    for (int i_ = 0; i_ < 16; ++i_) acc[i_] *= rs_; \
    Xw += (float)ex_; \
  } while (0)

      int sg = 0;
      while (sg + 8 <= v) {
        MSTEP(er0); er0 = MLDW(t0 + sg + 8);
        MSTEP(er1); er1 = MLDW(t0 + sg + 9);
        MSTEP(er2); er2 = MLDW(t0 + sg + 10);
        MSTEP(er3); er3 = MLDW(t0 + sg + 11);
        MSTEP(er4); er4 = MLDW(t0 + sg + 12);
        MSTEP(er5); er5 = MLDW(t0 + sg + 13);
        MSTEP(er6); er6 = MLDW(t0 + sg + 14);
        MSTEP(er7); er7 = MLDW(t0 + sg + 15);
        sg += 8;
      }
      if (sg + 0 < v) MSTEP(er0);
      if (sg + 1 < v) MSTEP(er1);
      if (sg + 2 < v) MSTEP(er2);
      if (sg + 3 < v) MSTEP(er3);
      if (sg + 4 < v) MSTEP(er4);
      if (sg + 5 < v) MSTEP(er5);
      if (sg + 6 < v) MSTEP(er6);
      if (sg + 7 < v) MSTEP(er7);

      {
        unsigned* mw32 = (unsigned*)&Mb[mi][0];
        #pragma unroll
        for (int j = 0; j < 8; ++j) {
          const int row0 = (2 * j & 3) + 8 * (2 * j >> 2) + 4 * half;
          mw32[(col * NL + row0) >> 1] = cvtpk(acc[2 * j], acc[2 * j + 1]);
        }
      }
      if (lane < 32) Xls[mi][col] = Xw;
#undef MSTEP
#undef MLDW
    }
  }

  __syncthreads();

  if (w == 0) {
    // ---------------- junction: alpha through M2, M3 (R18 phase-2, verbatim) ----------------
    bool curB = endB;
    for (int cdx = 0; cdx < 2; ++cdx) {
      const int held = curB ? labB : labA;
      const int outl = curB ? labA : labB;
      const float dX = Xls[cdx][held];
      const float X0 = __int_as_float(__builtin_amdgcn_readfirstlane(__float_as_int(dX)));
      u *= fexp2(fminf(dX - X0, 120.0f));
      ls += X0;
      RENU;
      float Ec[16];
#define LDE(K) Ec[K] = bf2f(Mb[cdx][roti<K>(held) * NL + outl]);
      LDE(0)  LDE(1)  LDE(2)  LDE(3)  LDE(4)  LDE(5)  LDE(6)  LDE(7)
      LDE(8)  LDE(9)  LDE(10) LDE(11) LDE(12) LDE(13) LDE(14) LDE(15)
#undef LDE
      const float s16 = tree16f(u, Ec);
      u = (!curB) ? COMB16(s16) : plswap32_sum(s16);
      RENU;
      curB = !curB;
    }
    slotm[curB ? labB : labA] = ls + flog2(u);
    asm volatile("s_waitcnt lgkmcnt(0)" ::: "memory");

    // Z = ln2 * LSE2_j(alphalog[j] + betalog[j])  (beta written pre-barrier by w3)
    float v2 = (lane < 32) ? (slotm[lane] + slotm[32 + lane]) : -3.0e38f;
    float mm = v2;
    #pragma unroll
    for (int ww = 32; ww; ww >>= 1) mm = fmaxf(mm, __shfl_xor(mm, ww));
    float ssum = fexp2(v2 - mm);
    #pragma unroll
    for (int ww = 32; ww; ww >>= 1) ssum += __shfl_xor(ssum, ww);
    if (lane == 0) atomicAdd(out + 0, LN2 * (mm + flog2(ssum)));
  } else if (w == 1) {
    // ---------------- labeled score (R13-validated) ----------------
    const int* tb = tags + (size_t)b * NS;
    float lab = 0.0f;
    if (lane == 0) {
      const int tg0 = tb[0];
      lab += Tld[31 * NL + tg0] + LOG2E * sbf[tg0];
      const int tgl = tb[len - 1];
      lab += Tld[tgl * NL + 30];
    }
    for (int t2 = 1 + lane; t2 < len; t2 += 64) {
      const int tp = tb[t2 - 1];
      const int tg = tb[t2];
      lab += Tld[tp * NL + tg] + LOG2E * sbf[(size_t)t2 * NL + tg];
    }
    #pragma unroll
    for (int ww = 32; ww; ww >>= 1) lab += __shfl_xor(lab, ww);
    if (lane == 0) atomicAdd(out + 1, LN2 * lab);
  }
#undef COMB16
#undef LDROW
#undef RENU
}

extern "C" void kernel_launch(void* const* d_in, const int* in_sizes, int n_in,
                              void* d_out, int out_size, void* d_ws, size_t ws_size,
                              hipStream_t stream) {
  const float* scores = (const float*)d_in[0];
  const float* trans  = (const float*)d_in[1];
  const int*   lens   = (const int*)d_in[2];
  const int*   tags   = (const int*)d_in[3];
  float* out = (float*)d_out;

  int* perm = (ws_size >= NB * sizeof(int)) ? (int*)d_ws : nullptr;

  zero_out_k<<<1, 64, 0, stream>>>(out);
  if (perm) sort_perm_k<<<1, 1024, 0, stream>>>(lens, perm);
  crf_fwd<<<NB, 256, 0, stream>>>(scores, trans, lens, tags, perm, out);
}

// Round 26
// 120.895 us; speedup vs baseline: 1.0933x; 1.0197x over previous
//
#include <hip/hip_runtime.h>

#define NB 2048
#define NS 1024
#define NL 32

static __device__ __forceinline__ float fexp2(float x) {
#if __has_builtin(__builtin_amdgcn_exp2f)
  return __builtin_amdgcn_exp2f(x);
#else
  float r; asm("v_exp_f32 %0, %1" : "=v"(r) : "v"(x)); return r;
#endif
}
static __device__ __forceinline__ float flog2(float x) {
#if __has_builtin(__builtin_amdgcn_logf)
  return __builtin_amdgcn_logf(x);
#else
  float r; asm("v_log_f32 %0, %1" : "=v"(r) : "v"(x)); return r;
#endif
}

template<int K>
static __device__ __forceinline__ int roti(int x) {
  if constexpr (K == 0) return x;
  else return __builtin_amdgcn_update_dpp(0, x, 0x120 | K, 0xf, 0xf, true); // row_ror:K
}

// part + part[pair(lane)] via permlane swaps with s_nop hazard guards (R10-validated).
static __device__ __forceinline__ float plswap16_sum(float part) {
  float x, y;
  asm volatile("v_mov_b32 %0, %2\n\t"
               "v_mov_b32 %1, %2\n\t"
               "s_nop 1\n\t"
               "v_permlane16_swap_b32 %0, %1\n\t"
               "s_nop 1"
               : "=&v"(x), "=&v"(y) : "v"(part));
  return x + y;
}
static __device__ __forceinline__ float plswap32_sum(float part) {
  float x, y;
  asm volatile("v_mov_b32 %0, %2\n\t"
               "v_mov_b32 %1, %2\n\t"
               "s_nop 1\n\t"
               "v_permlane32_swap_b32 %0, %1\n\t"
               "s_nop 1"
               : "=&v"(x), "=&v"(y) : "v"(part));
  return x + y;
}
static __device__ __forceinline__ int plswap16_partner(int lane) {
  int x, y;
  asm volatile("v_mov_b32 %0, %2\n\t"
               "v_mov_b32 %1, %2\n\t"
               "s_nop 1\n\t"
               "v_permlane16_swap_b32 %0, %1\n\t"
               "s_nop 1"
               : "=&v"(x), "=&v"(y) : "v"(lane));
  return x + y - lane;
}

// 16-term rotate/FMA tree, DPP-fused (R23-validated; same row_ror perm as roti<K>)
static __device__ __forceinline__ float tree16f(float p, const float* E) {
  float a0 = 0.0f, a1 = 0.0f, a2 = 0.0f, a3 = 0.0f;
  asm volatile(
    "s_nop 1\n\t"
    "v_mul_f32 %0, %4, %5\n\t"
    "v_mul_f32_dpp %1, %4, %6 row_ror:1 row_mask:0xf bank_mask:0xf\n\t"
    "v_mul_f32_dpp %2, %4, %7 row_ror:2 row_mask:0xf bank_mask:0xf\n\t"
    "v_mul_f32_dpp %3, %4, %8 row_ror:3 row_mask:0xf bank_mask:0xf\n\t"
    "v_fmac_f32_dpp %0, %4, %9 row_ror:4 row_mask:0xf bank_mask:0xf\n\t"
    "v_fmac_f32_dpp %1, %4, %10 row_ror:5 row_mask:0xf bank_mask:0xf\n\t"
    "v_fmac_f32_dpp %2, %4, %11 row_ror:6 row_mask:0xf bank_mask:0xf\n\t"
    "v_fmac_f32_dpp %3, %4, %12 row_ror:7 row_mask:0xf bank_mask:0xf\n\t"
    "v_fmac_f32_dpp %0, %4, %13 row_ror:8 row_mask:0xf bank_mask:0xf\n\t"
    "v_fmac_f32_dpp %1, %4, %14 row_ror:9 row_mask:0xf bank_mask:0xf\n\t"
    "v_fmac_f32_dpp %2, %4, %15 row_ror:10 row_mask:0xf bank_mask:0xf\n\t"
    "v_fmac_f32_dpp %3, %4, %16 row_ror:11 row_mask:0xf bank_mask:0xf\n\t"
    "v_fmac_f32_dpp %0, %4, %17 row_ror:12 row_mask:0xf bank_mask:0xf\n\t"
    "v_fmac_f32_dpp %1, %4, %18 row_ror:13 row_mask:0xf bank_mask:0xf\n\t"
    "v_fmac_f32_dpp %2, %4, %19 row_ror:14 row_mask:0xf bank_mask:0xf\n\t"
    "v_fmac_f32_dpp %3, %4, %20 row_ror:15 row_mask:0xf bank_mask:0xf"
    : "+v"(a0), "+v"(a1), "+v"(a2), "+v"(a3)
    : "v"(p),
      "v"(E[0]),  "v"(E[1]),  "v"(E[2]),  "v"(E[3]),
      "v"(E[4]),  "v"(E[5]),  "v"(E[6]),  "v"(E[7]),
      "v"(E[8]),  "v"(E[9]),  "v"(E[10]), "v"(E[11]),
      "v"(E[12]), "v"(E[13]), "v"(E[14]), "v"(E[15]));
  return (a0 + a1) + (a2 + a3);
}

__global__ void zero_out_k(float* out) {
  if (threadIdx.x < 2) out[threadIdx.x] = 0.0f;
}

// counting sort by descending length: perm[pos] = batch index, longest first.
__global__ __launch_bounds__(1024)
void sort_perm_k(const int* __restrict__ lens, int* __restrict__ perm) {
  __shared__ int h0[1024], h1[1024];
  const int tid = threadIdx.x;
  h0[tid] = 0;
  __syncthreads();
  for (int i = tid; i < NB; i += 1024) atomicAdd(&h0[1024 - lens[i]], 1);
  __syncthreads();
  const int cnt = h0[tid];
  int* src = h0; int* dst = h1;
  for (int off = 1; off < 1024; off <<= 1) {
    dst[tid] = src[tid] + ((tid >= off) ? src[tid - off] : 0);
    __syncthreads();
    int* tmp = src; src = dst; dst = tmp;
  }
  const int excl = src[tid] - cnt;
  __syncthreads();
  dst[tid] = excl;
  __syncthreads();
  for (int i = tid; i < NB; i += 1024) {
    const int key = 1024 - lens[i];
    const int pos = atomicAdd(&dst[key], 1);
    perm[pos] = i;
  }
}

// 2 waves/block: wave0 = forward alpha chain, wave1 = backward beta chain.
// Emits gathered DIRECTLY from global into an 8-deep register pipeline.
// LPT block order via perm (R22-validated). DPP-fused tree (R23).
__global__ __launch_bounds__(128, 2)
void crf_fwd(const float* __restrict__ scores, const float* __restrict__ trans,
             const int* __restrict__ lens, const int* __restrict__ tags,
             const int* __restrict__ perm, float* __restrict__ out)
{
  constexpr float LOG2E = 1.4426950408889634f;
  constexpr float LN2   = 0.6931471805599453f;
  __shared__ float Tld[NL * NL];
  __shared__ float slotm[64];

  const int b    = perm ? perm[blockIdx.x] : blockIdx.x;
  const int tid  = threadIdx.x;
  const int wid  = tid >> 6;
  const int lane = tid & 63;
  const int len  = lens[b];
  const int m    = len >> 1;            // forward: m steps -> alpha_m
  const int nB   = len - 1 - m;         // backward: nB steps -> beta_m
  const int r = lane >> 4, c = lane & 15;
  const int labA = c + ((r & 1) << 4);

  const int p16 = plswap16_partner(lane);
  const bool plOK = ((p16 & 15) == c) && ((((p16 >> 4) ^ r) & 1) == 1);
  const int pmax = (lane > p16) ? lane : p16;
  const int labB = plOK ? (c + ((pmax >= 48) ? 16 : 0))
                        : (c + (((r >> 1) & 1) << 4));

  const float* sbf = scores + (size_t)b * (NS * NL);

  for (int k2 = tid; k2 < NL * NL; k2 += 128) Tld[k2] = trans[k2] * LOG2E;
  __syncthreads();

#define COMB16(S) (plOK ? plswap16_sum(S) : ((S) + __shfl_xor((S), 16)))
// clamped global emit gather: row in [0, len-1]; one 128B line per load
#define LDROW(DST, ROW, LAB) do { \
    int r_ = (ROW); r_ = r_ < 0 ? 0 : r_; r_ = r_ > len - 1 ? len - 1 : r_; \
    DST = sbf[(size_t)r_ * NL + (LAB)]; \
  } while (0)

  float u, ls;
  bool endB = false;

  if (wid == 0) {
    // ---------------- forward ----------------
    float EA[16], EB[16];
#define CFA(K) EA[K] = fexp2(Tld[roti<K>(labA) * NL + labB]);
#define CFB(K) EB[K] = fexp2(Tld[roti<K>(labB) * NL + labA]);
    CFA(0)  CFA(1)  CFA(2)  CFA(3)  CFA(4)  CFA(5)  CFA(6)  CFA(7)
    CFA(8)  CFA(9)  CFA(10) CFA(11) CFA(12) CFA(13) CFA(14) CFA(15)
    CFB(0)  CFB(1)  CFB(2)  CFB(3)  CFB(4)  CFB(5)  CFB(6)  CFB(7)
    CFB(8)  CFB(9)  CFB(10) CFB(11) CFB(12) CFB(13) CFB(14) CFB(15)
#undef CFA
#undef CFB
    float a0 = Tld[31 * NL + labA] + LOG2E * sbf[labA];
    ls = __int_as_float(__builtin_amdgcn_readfirstlane(__float_as_int(a0)));
    u = fexp2(a0 - ls);

#define RENORM do { \
    const int eb_ = __builtin_amdgcn_readfirstlane(__float_as_int(u)); \
    const int ex_ = (eb_ >> 23) - 127; \
    ls += (float)ex_; \
    u *= __int_as_float((127 - ex_) << 23); \
  } while (0)

    // 8-deep emit pipeline: P = steps t..t+3, Q = t+4..t+7
    float P0, P1, P2, P3, Q0, Q1, Q2, Q3;
    int t = 1;
    LDROW(P0, 1, labB); LDROW(P1, 2, labA); LDROW(P2, 3, labB); LDROW(P3, 4, labA);
    LDROW(Q0, 5, labB); LDROW(Q1, 6, labA); LDROW(Q2, 7, labB); LDROW(Q3, 8, labA);

#define FBODY(B0, B1, B2, B3) do { \
    RENORM; \
    const float w0 = fexp2(B0 * LOG2E); \
    const float w1 = fexp2(B1 * LOG2E); \
    const float w2 = fexp2(B2 * LOG2E); \
    const float w3 = fexp2(B3 * LOG2E); \
    LDROW(B0, t + 8,  labB); LDROW(B1, t + 9,  labA); \
    LDROW(B2, t + 10, labB); LDROW(B3, t + 11, labA); \
    u = COMB16(tree16f(u, EA)) * w0; \
    u = plswap32_sum(tree16f(u, EB)) * w1; \
    u = COMB16(tree16f(u, EA)) * w2; \
    u = plswap32_sum(tree16f(u, EB)) * w3; \
  } while (0)

    while (t + 7 <= m) {
      FBODY(P0, P1, P2, P3); t += 4;
      FBODY(Q0, Q1, Q2, Q3); t += 4;
    }
    if (t + 3 <= m) { FBODY(P0, P1, P2, P3); t += 4; }
    // drain (<=3 steps), direct loads
    while (t <= m) {
      if ((t & 3) == 1) RENORM;
      if (t & 1) {          // A-step
        float e; LDROW(e, t, labB);
        u = COMB16(tree16f(u, EA)) * fexp2(e * LOG2E);
        endB = true;
      } else {              // B-step
        float e; LDROW(e, t, labA);
        u = plswap32_sum(tree16f(u, EB)) * fexp2(e * LOG2E);
        endB = false;
      }
      t++;
    }
#undef FBODY
  } else {
    // ---------------- backward ----------------
    float EA[16], EB[16];
#define CBA(K) EA[K] = fexp2(Tld[labB * NL + roti<K>(labA)]);
#define CBB(K) EB[K] = fexp2(Tld[labA * NL + roti<K>(labB)]);
    CBA(0)  CBA(1)  CBA(2)  CBA(3)  CBA(4)  CBA(5)  CBA(6)  CBA(7)
    CBA(8)  CBA(9)  CBA(10) CBA(11) CBA(12) CBA(13) CBA(14) CBA(15)
    CBB(0)  CBB(1)  CBB(2)  CBB(3)  CBB(4)  CBB(5)  CBB(6)  CBB(7)
    CBB(8)  CBB(9)  CBB(10) CBB(11) CBB(12) CBB(13) CBB(14) CBB(15)
#undef CBA
#undef CBB
    float a0 = Tld[labA * NL + 30];
    ls = __int_as_float(__builtin_amdgcn_readfirstlane(__float_as_int(a0)));
    u = fexp2(a0 - ls);

#define RENORMB do { \
    const int eb_ = __builtin_amdgcn_readfirstlane(__float_as_int(u)); \
    const int ex_ = (eb_ >> 23) - 127; \
    ls += (float)ex_; \
    u *= __int_as_float((127 - ex_) << 23); \
  } while (0)

    float P0, P1, P2, P3, Q0, Q1, Q2, Q3;
    int k = 0;
    LDROW(P0, len - 1, labA); LDROW(P1, len - 2, labB);
    LDROW(P2, len - 3, labA); LDROW(P3, len - 4, labB);
    LDROW(Q0, len - 5, labA); LDROW(Q1, len - 6, labB);
    LDROW(Q2, len - 7, labA); LDROW(Q3, len - 8, labB);

#define BBODY(B0, B1, B2, B3) do { \
    RENORMB; \
    const float w0 = fexp2(B0 * LOG2E); \
    const float w1 = fexp2(B1 * LOG2E); \
    const float w2 = fexp2(B2 * LOG2E); \
    const float w3 = fexp2(B3 * LOG2E); \
    LDROW(B0, len - 1 - k - 8,  labA); LDROW(B1, len - 2 - k - 8,  labB); \
    LDROW(B2, len - 3 - k - 8,  labA); LDROW(B3, len - 4 - k - 8,  labB); \
    u = COMB16(tree16f(u * w0, EA)); \
    u = plswap32_sum(tree16f(u * w1, EB)); \
    u = COMB16(tree16f(u * w2, EA)); \
    u = plswap32_sum(tree16f(u * w3, EB)); \
  } while (0)

    while (k + 7 < nB) {
      BBODY(P0, P1, P2, P3); k += 4;
      BBODY(Q0, Q1, Q2, Q3); k += 4;
    }
    if (k + 3 < nB) { BBODY(P0, P1, P2, P3); k += 4; }
    while (k < nB) {
      if ((k & 3) == 0) RENORMB;
      if (!(k & 1)) {       // A-step
        float e; LDROW(e, len - 1 - k, labA);
        u = COMB16(tree16f(u * fexp2(e * LOG2E), EA));
        endB = true;
      } else {              // B-step
        float e; LDROW(e, len - 1 - k, labB);
        u = plswap32_sum(tree16f(u * fexp2(e * LOG2E), EB));
        endB = false;
      }
      k++;
    }
#undef BBODY
#undef RENORMB
  }

  // -------- junction: Z = ln2 * LSE2_j(alphalog[j] + betalog[j]) --------
  slotm[wid * 32 + (endB ? labB : labA)] = ls + flog2(u);
  __syncthreads();

  if (wid == 0) {
    float v2 = (lane < 32) ? (slotm[lane] + slotm[32 + lane]) : -3.0e38f;
    float mm = v2;
    #pragma unroll
    for (int w = 32; w; w >>= 1) mm = fmaxf(mm, __shfl_xor(mm, w));
    float ssum = fexp2(v2 - mm);
    #pragma unroll
    for (int w = 32; w; w >>= 1) ssum += __shfl_xor(ssum, w);
    if (lane == 0) atomicAdd(out + 0, LN2 * (mm + flog2(ssum)));

    // -------- labeled score --------
    const int* tb = tags + (size_t)b * NS;
    float lab = 0.0f;
    if (lane == 0) {
      const int tg0 = tb[0];
      lab += Tld[31 * NL + tg0] + LOG2E * sbf[tg0];
      const int tgl = tb[len - 1];
      lab += Tld[tgl * NL + 30];
    }
    for (int t2 = 1 + lane; t2 < len; t2 += 64) {
      const int tp = tb[t2 - 1];
      const int tg = tb[t2];
      lab += Tld[tp * NL + tg] + LOG2E * sbf[(size_t)t2 * NL + tg];
    }
    #pragma unroll
    for (int w = 32; w; w >>= 1) lab += __shfl_xor(lab, w);
    if (lane == 0) atomicAdd(out + 1, LN2 * lab);
  }
#undef COMB16
#undef LDROW
#undef RENORM
}

extern "C" void kernel_launch(void* const* d_in, const int* in_sizes, int n_in,
                              void* d_out, int out_size, void* d_ws, size_t ws_size,
                              hipStream_t stream) {
  const float* scores = (const float*)d_in[0];
  const float* trans  = (const float*)d_in[1];
  const int*   lens   = (const int*)d_in[2];
  const int*   tags   = (const int*)d_in[3];
  float* out = (float*)d_out;

  int* perm = (ws_size >= NB * sizeof(int)) ? (int*)d_ws : nullptr;

  zero_out_k<<<1, 64, 0, stream>>>(out);
  if (perm) sort_perm_k<<<1, 1024, 0, stream>>>(lens, perm);
  crf_fwd<<<NB, 128, 0, stream>>>(scores, trans, lens, tags, perm, out);
}